// Round 3
// baseline (269.401 us; speedup 1.0000x reference)
//
#include <hip/hip_runtime.h>

typedef __attribute__((ext_vector_type(4))) float    f32x4;
typedef __attribute__((ext_vector_type(4))) short    s16x4;
typedef __attribute__((ext_vector_type(8))) short    s16x8;

#define ROWS 16
#define XS_STRIDE 520   // 512 + 8 bf16 pad

__device__ __forceinline__ short f2bf(float f) {
  unsigned u = __float_as_uint(f);
  u = (u + 0x7fffu + ((u >> 16) & 1u)) >> 16;   // RNE
  return (short)u;
}

// ---------------- precompute ----------------
// wF[d2][vt][kt][lane][j] = lin_w[d2][k][v] / sqrt(128), bf16
//   v = vt*16 + (lane&15), k = kt*32 + (lane>>4)*8 + j
// cc[v][ab][j] (f32, stride 24): j<16 -> C3u[c=j>>2][i=j&3], j in 16..19 -> C2u[i=j-16]
// cu1[v][a*4+i] (f32)
__global__ void precompute_kernel(const float* __restrict__ lin_w,
                                  const float* __restrict__ w1,
                                  const float* __restrict__ w2,
                                  const float* __restrict__ w3,
                                  const float* __restrict__ C1,
                                  const float* __restrict__ C2,
                                  const float* __restrict__ C3,
                                  short*    __restrict__ wF,
                                  float*    __restrict__ cc,
                                  float*    __restrict__ cu1) {
  int tid = blockIdx.x * blockDim.x + threadIdx.x;
  int nth = gridDim.x * blockDim.x;
  const float rs = 0.088388347648318447f;  // 1/sqrt(128)
  // weight fragments, coalesced per-wave layout, rs folded in
  for (int idx = tid; idx < 6 * 8 * 4 * 64 * 8; idx += nth) {
    int j  = idx & 7;
    int ln = (idx >> 3) & 63;
    int kt = (idx >> 9) & 3;
    int vt = (idx >> 11) & 7;
    int d2 = idx >> 14;
    int v  = vt * 16 + (ln & 15);
    int k  = kt * 32 + (ln >> 4) * 8 + j;
    wF[idx] = f2bf(lin_w[(d2 * 128 + k) * 128 + v] * rs);
  }
  // fused C2u/C3u table (f32)
  for (int idx = tid; idx < 128 * 16 * 20; idx += nth) {
    int v  = idx / 320;
    int r  = idx - v * 320;
    int ab = r / 20;
    int j  = r - ab * 20;
    int a = ab >> 2, b = ab & 3;
    float s = 0.f;
    if (j < 16) {
      int c = j >> 2, i = j & 3;
      const float* p = C3 + (((a * 4 + b) * 4 + c) * 4 + i) * 12;
      #pragma unroll
      for (int w = 0; w < 12; ++w) s += p[w] * w3[w * 128 + v];
    } else {
      int i = j - 16;
      const float* p = C2 + ((a * 4 + b) * 4 + i) * 5;
      #pragma unroll
      for (int w = 0; w < 5; ++w) s += p[w] * w2[w * 128 + v];
    }
    cc[(v * 16 + ab) * 24 + j] = s;
  }
  // cu1[v][a*4+i]
  for (int idx = tid; idx < 128 * 16; idx += nth) {
    int v = idx >> 4;
    int ai = idx & 15;
    int a = ai >> 2, i = ai & 3;
    cu1[idx] = C1[(a * 4 + i) * 2 + 0] * w1[v] + C1[(a * 4 + i) * 2 + 1] * w1[128 + v];
  }
}

// ---------------- fused main: MFMA linear (y in regs) + fp32 contraction ----------------
// 512 threads = 8 waves; wave w owns vt = w (v = w*16 + vl). One 16-row tile per block.
__launch_bounds__(512, 4)
__global__ void main_kernel(const float* __restrict__ x,
                            const short* __restrict__ wF,
                            const float* __restrict__ cc,
                            const float* __restrict__ cu1,
                            float* __restrict__ out) {
  __shared__ short xs[ROWS * XS_STRIDE];   // [row][a*128+k], bf16

  const int t    = threadIdx.x;
  const int lane = t & 63;
  const int wave = t >> 6;      // 0..7 == vt
  const int vl   = lane & 15;
  const int quad = lane >> 4;   // 0..3
  const int n0   = blockIdx.x * ROWS;

  // issue d2=0 weight-fragment loads first (overlap with x staging + barrier)
  s16x8 bf_cur[4], bf_nxt[4];
  {
    const s16x8* wsrc = (const s16x8*)wF + wave * 256 + lane;
    #pragma unroll
    for (int kt = 0; kt < 4; ++kt) bf_cur[kt] = wsrc[kt * 64];
  }

  // stage x tile -> bf16 LDS (coalesced float4 loads)
  const float4* xsrc = (const float4*)(x + (size_t)n0 * 512);
  #pragma unroll
  for (int i2 = 0; i2 < 4; ++i2) {
    int f = i2 * 512 + t;          // float4 id, 0..2047
    float4 xv = xsrc[f];
    int row = f >> 7, c4 = f & 127;
    s16x4 pk;
    pk[0] = f2bf(xv.x); pk[1] = f2bf(xv.y); pk[2] = f2bf(xv.z); pk[3] = f2bf(xv.w);
    *(s16x4*)&xs[row * XS_STRIDE + c4 * 4] = pk;
  }
  __syncthreads();

  // y[da][r]: da = d*4+a; this wave's v = wave*16+vl; row = quad*4+r
  float yreg[12][4];

  #pragma unroll
  for (int d2 = 0; d2 < 6; ++d2) {
    // prefetch next (d,blk) weight fragments while this one computes
    if (d2 < 5) {
      const s16x8* wsrc = (const s16x8*)wF + ((d2 + 1) * 8 + wave) * 256 + lane;
      #pragma unroll
      for (int kt = 0; kt < 4; ++kt) bf_nxt[kt] = wsrc[kt * 64];
    }
    const int d = d2 >> 1, blk = d2 & 1;
    const int a_begin = blk ? 1 : 0;
    const int a_end   = blk ? 4 : 1;
    #pragma unroll
    for (int a = a_begin; a < a_end; ++a) {
      f32x4 acc = {0.f, 0.f, 0.f, 0.f};
      #pragma unroll
      for (int kt = 0; kt < 4; ++kt) {
        s16x8 af = *(const s16x8*)&xs[vl * XS_STRIDE + a * 128 + kt * 32 + quad * 8];
        acc = __builtin_amdgcn_mfma_f32_16x16x32_bf16(af, bf_cur[kt], acc, 0, 0, 0);
      }
      const int da = d * 4 + a;
      #pragma unroll
      for (int r = 0; r < 4; ++r) yreg[da][r] = acc[r];
    }
    #pragma unroll
    for (int kt = 0; kt < 4; ++kt) bf_cur[kt] = bf_nxt[kt];
  }

  // ---------------- contraction (fp32, y in regs, f32 coeffs double-buffered from L2) ----
  const int v = wave * 16 + vl;
  float acc[4][4];   // [i][r]

  // degree 1
  {
    const f32x4* cu1v = (const f32x4*)(cu1 + v * 16);
    float c1[16];
    #pragma unroll
    for (int q = 0; q < 4; ++q) {
      f32x4 tv = cu1v[q];
      c1[4 * q + 0] = tv[0]; c1[4 * q + 1] = tv[1]; c1[4 * q + 2] = tv[2]; c1[4 * q + 3] = tv[3];
    }
    #pragma unroll
    for (int i = 0; i < 4; ++i)
      #pragma unroll
      for (int r = 0; r < 4; ++r) {
        float s = c1[0 * 4 + i] * yreg[0][r];
        s = fmaf(c1[1 * 4 + i], yreg[1][r], s);
        s = fmaf(c1[2 * 4 + i], yreg[2][r], s);
        s = fmaf(c1[3 * 4 + i], yreg[3][r], s);
        acc[i][r] = s;
      }
  }

  // degrees 2+3: out[i] += G[ab] * (C2u[ab,i] + sum_c C3u[ab,c,i]*y3[c])
  const float* ccv = cc + v * 384;   // 16 * 24
  f32x4 cva[5], cvb[5];
  #pragma unroll
  for (int q = 0; q < 5; ++q) cva[q] = *(const f32x4*)(ccv + q * 4);
  #pragma unroll
  for (int ab = 0; ab < 16; ++ab) {
    // prefetch next iteration's coefficients (wraps to ab=0 on last iter; in-bounds)
    const int abn = (ab + 1) & 15;
    #pragma unroll
    for (int q = 0; q < 5; ++q) cvb[q] = *(const f32x4*)(ccv + abn * 24 + q * 4);
    const int a = ab >> 2, b = ab & 3;
    float cj[20];
    #pragma unroll
    for (int q = 0; q < 5; ++q) {
      cj[q * 4 + 0] = cva[q][0]; cj[q * 4 + 1] = cva[q][1];
      cj[q * 4 + 2] = cva[q][2]; cj[q * 4 + 3] = cva[q][3];
    }
    #pragma unroll
    for (int r = 0; r < 4; ++r) {
      const float G = yreg[a][r] * yreg[4 + b][r];
      #pragma unroll
      for (int i = 0; i < 4; ++i) {
        float s = cj[16 + i];
        s = fmaf(cj[0 + i],  yreg[8][r],  s);
        s = fmaf(cj[4 + i],  yreg[9][r],  s);
        s = fmaf(cj[8 + i],  yreg[10][r], s);
        s = fmaf(cj[12 + i], yreg[11][r], s);
        acc[i][r] = fmaf(G, s, acc[i][r]);
      }
    }
    #pragma unroll
    for (int q = 0; q < 5; ++q) cva[q] = cvb[q];
  }

  // store
  #pragma unroll
  for (int r = 0; r < 4; ++r) {
    const int n = n0 + quad * 4 + r;
    #pragma unroll
    for (int i = 0; i < 4; ++i) out[(size_t)n * 512 + i * 128 + v] = acc[i][r];
  }
}

extern "C" void kernel_launch(void* const* d_in, const int* in_sizes, int n_in,
                              void* d_out, int out_size, void* d_ws, size_t ws_size,
                              hipStream_t stream) {
  const float* x     = (const float*)d_in[0];
  const float* lin_w = (const float*)d_in[1];
  const float* w1    = (const float*)d_in[2];
  const float* w2    = (const float*)d_in[3];
  const float* w3    = (const float*)d_in[4];
  const float* C1    = (const float*)d_in[5];
  const float* C2    = (const float*)d_in[6];
  const float* C3    = (const float*)d_in[7];

  char* ws = (char*)d_ws;
  short* wF  = (short*)ws;                     // 196608 B
  float* cc  = (float*)(ws + 196608);          // 196608 B (f32 now)
  float* cu1 = (float*)(ws + 393216);          //   8192 B
  float* out = (float*)d_out;

  hipLaunchKernelGGL(precompute_kernel, dim3(384), dim3(256), 0, stream,
                     lin_w, w1, w2, w3, C1, C2, C3, wF, cc, cu1);
  hipLaunchKernelGGL(main_kernel, dim3(2048), dim3(512), 0, stream,
                     x, wF, cc, cu1, out);
}

// Round 4
// 213.049 us; speedup vs baseline: 1.2645x; 1.2645x over previous
//
#include <hip/hip_runtime.h>

typedef __attribute__((ext_vector_type(4))) float    f32x4;
typedef __attribute__((ext_vector_type(4))) short    s16x4;
typedef __attribute__((ext_vector_type(8))) short    s16x8;
typedef __attribute__((ext_vector_type(8))) _Float16 h16x8;

#define ROWS 16
#define XS_STRIDE 520   // 512 + 8 bf16 pad

__device__ __forceinline__ short f2bf(float f) {
  unsigned u = __float_as_uint(f);
  u = (u + 0x7fffu + ((u >> 16) & 1u)) >> 16;   // RNE
  return (short)u;
}

// ---------------- precompute ----------------
// wF[d2][vt][kt][lane][j] = lin_w[d2][k][v] / sqrt(128), bf16
//   v = vt*16 + (lane&15), k = kt*32 + (lane>>4)*8 + j
// cc[v][ab][j] (fp16, stride 24): j<16 -> C3u[c=j>>2][i=j&3], j in 16..19 -> C2u[i=j-16]
// cu1[v][a*4+i] (f32)
__global__ void precompute_kernel(const float* __restrict__ lin_w,
                                  const float* __restrict__ w1,
                                  const float* __restrict__ w2,
                                  const float* __restrict__ w3,
                                  const float* __restrict__ C1,
                                  const float* __restrict__ C2,
                                  const float* __restrict__ C3,
                                  short*    __restrict__ wF,
                                  _Float16* __restrict__ cc,
                                  float*    __restrict__ cu1) {
  int tid = blockIdx.x * blockDim.x + threadIdx.x;
  int nth = gridDim.x * blockDim.x;
  const float rs = 0.088388347648318447f;  // 1/sqrt(128)
  // weight fragments, coalesced per-wave layout, rs folded in
  for (int idx = tid; idx < 6 * 8 * 4 * 64 * 8; idx += nth) {
    int j  = idx & 7;
    int ln = (idx >> 3) & 63;
    int kt = (idx >> 9) & 3;
    int vt = (idx >> 11) & 7;
    int d2 = idx >> 14;
    int v  = vt * 16 + (ln & 15);
    int k  = kt * 32 + (ln >> 4) * 8 + j;
    wF[idx] = f2bf(lin_w[(d2 * 128 + k) * 128 + v] * rs);
  }
  // fused C2u/C3u table (fp16)
  for (int idx = tid; idx < 128 * 16 * 20; idx += nth) {
    int v  = idx / 320;
    int r  = idx - v * 320;
    int ab = r / 20;
    int j  = r - ab * 20;
    int a = ab >> 2, b = ab & 3;
    float s = 0.f;
    if (j < 16) {
      int c = j >> 2, i = j & 3;
      const float* p = C3 + (((a * 4 + b) * 4 + c) * 4 + i) * 12;
      #pragma unroll
      for (int w = 0; w < 12; ++w) s += p[w] * w3[w * 128 + v];
    } else {
      int i = j - 16;
      const float* p = C2 + ((a * 4 + b) * 4 + i) * 5;
      #pragma unroll
      for (int w = 0; w < 5; ++w) s += p[w] * w2[w * 128 + v];
    }
    cc[(v * 16 + ab) * 24 + j] = (_Float16)s;
  }
  // cu1[v][a*4+i]
  for (int idx = tid; idx < 128 * 16; idx += nth) {
    int v = idx >> 4;
    int ai = idx & 15;
    int a = ai >> 2, i = ai & 3;
    cu1[idx] = C1[(a * 4 + i) * 2 + 0] * w1[v] + C1[(a * 4 + i) * 2 + 1] * w1[128 + v];
  }
}

// ---------------- fused main: MFMA linear (y in regs) + fp32 contraction ----------------
// 512 threads = 8 waves; wave w owns vt = w (v = w*16 + vl). One 16-row tile per block.
// Software pipelining is ENFORCED with sched_barrier(0) after each prefetch-issue block:
// the compiler otherwise sinks prefetch loads back to their uses (rounds 2-3 evidence).
__launch_bounds__(512, 4)
__global__ void main_kernel(const float* __restrict__ x,
                            const short* __restrict__ wF,
                            const _Float16* __restrict__ cc,
                            const float* __restrict__ cu1,
                            float* __restrict__ out) {
  __shared__ short xs[ROWS * XS_STRIDE];   // [row][a*128+k], bf16

  const int t    = threadIdx.x;
  const int lane = t & 63;
  const int wave = t >> 6;      // 0..7 == vt
  const int vl   = lane & 15;
  const int quad = lane >> 4;   // 0..3
  const int n0   = blockIdx.x * ROWS;
  const int v    = wave * 16 + vl;

  // ---- early issue: wF[d2=0] fragments, cu1, cc[ab=0] (hidden under staging+barrier) ----
  s16x8 bf_cur[4], bf_nxt[4];
  {
    const s16x8* w0 = (const s16x8*)wF + wave * 256 + lane;
    #pragma unroll
    for (int kt = 0; kt < 4; ++kt) bf_cur[kt] = w0[kt * 64];
  }
  f32x4 c1v[4];
  {
    const f32x4* cu1v = (const f32x4*)(cu1 + v * 16);
    #pragma unroll
    for (int q = 0; q < 4; ++q) c1v[q] = cu1v[q];
  }
  const _Float16* ccv = cc + v * 384;   // 16 * 24 fp16
  h16x8 ha[3], hb[3];
  ha[0] = *(const h16x8*)(ccv + 0);
  ha[1] = *(const h16x8*)(ccv + 8);
  ha[2] = *(const h16x8*)(ccv + 16);
  __builtin_amdgcn_sched_barrier(0);

  // stage x tile -> bf16 LDS (coalesced float4 loads)
  const float4* xsrc = (const float4*)(x + (size_t)n0 * 512);
  #pragma unroll
  for (int i2 = 0; i2 < 4; ++i2) {
    int f = i2 * 512 + t;          // float4 id, 0..2047
    float4 xv = xsrc[f];
    int row = f >> 7, c4 = f & 127;
    s16x4 pk;
    pk[0] = f2bf(xv.x); pk[1] = f2bf(xv.y); pk[2] = f2bf(xv.z); pk[3] = f2bf(xv.w);
    *(s16x4*)&xs[row * XS_STRIDE + c4 * 4] = pk;
  }
  __syncthreads();

  // y[da][r]: da = d*4+a; this wave's v = wave*16+vl; row = quad*4+r
  float yreg[12][4];

  #pragma unroll
  for (int d2 = 0; d2 < 6; ++d2) {
    // prefetch next (d,blk) weight fragments; fence so they cannot sink into the MFMAs
    if (d2 < 5) {
      const s16x8* wsrc = (const s16x8*)wF + ((d2 + 1) * 8 + wave) * 256 + lane;
      #pragma unroll
      for (int kt = 0; kt < 4; ++kt) bf_nxt[kt] = wsrc[kt * 64];
    }
    __builtin_amdgcn_sched_barrier(0);
    const int d = d2 >> 1, blk = d2 & 1;
    const int a_begin = blk ? 1 : 0;
    const int a_end   = blk ? 4 : 1;
    #pragma unroll
    for (int a = a_begin; a < a_end; ++a) {
      f32x4 acc = {0.f, 0.f, 0.f, 0.f};
      #pragma unroll
      for (int kt = 0; kt < 4; ++kt) {
        s16x8 af = *(const s16x8*)&xs[vl * XS_STRIDE + a * 128 + kt * 32 + quad * 8];
        acc = __builtin_amdgcn_mfma_f32_16x16x32_bf16(af, bf_cur[kt], acc, 0, 0, 0);
      }
      const int da = d * 4 + a;
      #pragma unroll
      for (int r = 0; r < 4; ++r) yreg[da][r] = acc[r];
    }
    #pragma unroll
    for (int kt = 0; kt < 4; ++kt) bf_cur[kt] = bf_nxt[kt];
  }

  // ---------------- contraction (fp32 math, fp16 coeffs, fenced double-buffer) ----------
  float acc[4][4];   // [i][r]

  // degree 1 (c1v loaded at kernel top)
  {
    float c1[16];
    #pragma unroll
    for (int q = 0; q < 4; ++q) {
      c1[4 * q + 0] = c1v[q][0]; c1[4 * q + 1] = c1v[q][1];
      c1[4 * q + 2] = c1v[q][2]; c1[4 * q + 3] = c1v[q][3];
    }
    #pragma unroll
    for (int i = 0; i < 4; ++i)
      #pragma unroll
      for (int r = 0; r < 4; ++r) {
        float s = c1[0 * 4 + i] * yreg[0][r];
        s = fmaf(c1[1 * 4 + i], yreg[1][r], s);
        s = fmaf(c1[2 * 4 + i], yreg[2][r], s);
        s = fmaf(c1[3 * 4 + i], yreg[3][r], s);
        acc[i][r] = s;
      }
  }

  // degrees 2+3: out[i] += G[ab] * (C2u[ab,i] + sum_c C3u[ab,c,i]*y3[c])
  #pragma unroll
  for (int ab = 0; ab < 16; ++ab) {
    // prefetch next iteration's coefficients; fence so they cannot sink into compute
    const int abn = (ab + 1) & 15;
    hb[0] = *(const h16x8*)(ccv + abn * 24 + 0);
    hb[1] = *(const h16x8*)(ccv + abn * 24 + 8);
    hb[2] = *(const h16x8*)(ccv + abn * 24 + 16);
    __builtin_amdgcn_sched_barrier(0);

    const int a = ab >> 2, b = ab & 3;
    float cj[20];
    #pragma unroll
    for (int j = 0; j < 8; ++j) { cj[j] = (float)ha[0][j]; cj[8 + j] = (float)ha[1][j]; }
    #pragma unroll
    for (int j = 0; j < 4; ++j) cj[16 + j] = (float)ha[2][j];
    #pragma unroll
    for (int r = 0; r < 4; ++r) {
      const float G = yreg[a][r] * yreg[4 + b][r];
      #pragma unroll
      for (int i = 0; i < 4; ++i) {
        float s = cj[16 + i];
        s = fmaf(cj[0 + i],  yreg[8][r],  s);
        s = fmaf(cj[4 + i],  yreg[9][r],  s);
        s = fmaf(cj[8 + i],  yreg[10][r], s);
        s = fmaf(cj[12 + i], yreg[11][r], s);
        acc[i][r] = fmaf(G, s, acc[i][r]);
      }
    }
    #pragma unroll
    for (int q = 0; q < 3; ++q) ha[q] = hb[q];
  }

  // store
  #pragma unroll
  for (int r = 0; r < 4; ++r) {
    const int n = n0 + quad * 4 + r;
    #pragma unroll
    for (int i = 0; i < 4; ++i) out[(size_t)n * 512 + i * 128 + v] = acc[i][r];
  }
}

extern "C" void kernel_launch(void* const* d_in, const int* in_sizes, int n_in,
                              void* d_out, int out_size, void* d_ws, size_t ws_size,
                              hipStream_t stream) {
  const float* x     = (const float*)d_in[0];
  const float* lin_w = (const float*)d_in[1];
  const float* w1    = (const float*)d_in[2];
  const float* w2    = (const float*)d_in[3];
  const float* w3    = (const float*)d_in[4];
  const float* C1    = (const float*)d_in[5];
  const float* C2    = (const float*)d_in[6];
  const float* C3    = (const float*)d_in[7];

  char* ws = (char*)d_ws;
  short*    wF  = (short*)ws;                     // 196608 B
  _Float16* cc  = (_Float16*)(ws + 196608);       //  98304 B
  float*    cu1 = (float*)(ws + 294912);          //   8192 B
  float*    out = (float*)d_out;

  hipLaunchKernelGGL(precompute_kernel, dim3(384), dim3(256), 0, stream,
                     lin_w, w1, w2, w3, C1, C2, C3, wF, cc, cu1);
  hipLaunchKernelGGL(main_kernel, dim3(2048), dim3(512), 0, stream,
                     x, wF, cc, cu1, out);
}

// Round 6
// 185.412 us; speedup vs baseline: 1.4530x; 1.1491x over previous
//
#include <hip/hip_runtime.h>

typedef __attribute__((ext_vector_type(4))) float    f32x4;
typedef __attribute__((ext_vector_type(4))) short    s16x4;
typedef __attribute__((ext_vector_type(8))) short    s16x8;
typedef __attribute__((ext_vector_type(8))) _Float16 h16x8;

#define ROWS 16
#define XS_STRIDE 520   // 512 + 8 bf16 pad

__device__ __forceinline__ short f2bf(float f) {
  unsigned u = __float_as_uint(f);
  u = (u + 0x7fffu + ((u >> 16) & 1u)) >> 16;   // RNE
  return (short)u;
}

// ---------------- precompute ----------------
// wF[d2][vt][kt][lane][j] = lin_w[d2][k][v] / sqrt(128), bf16
//   v = vt*16 + (lane&15), k = kt*32 + (lane>>4)*8 + j
// cc: per-v rows of 768 bytes (16 ab-groups x 48 B), fp16, with the XOR swizzle
//   byte_in_row ^= (v&7)<<4 BAKED INTO THE GLOBAL LAYOUT, so the main kernel's
//   global->LDS copy is a linear identity copy and LDS reads use the same XOR
//   (spreads the 16 vl lanes of a wave across 8 bank groups -> 2-way = free).
//   group ab, j<16 -> C3u[c=j>>2][i=j&3], j in 16..19 -> C2u[i=j-16]
// cu1[v][a*4+i] (f32)
__global__ void precompute_kernel(const float* __restrict__ lin_w,
                                  const float* __restrict__ w1,
                                  const float* __restrict__ w2,
                                  const float* __restrict__ w3,
                                  const float* __restrict__ C1,
                                  const float* __restrict__ C2,
                                  const float* __restrict__ C3,
                                  short*    __restrict__ wF,
                                  _Float16* __restrict__ cc,
                                  float*    __restrict__ cu1) {
  int tid = blockIdx.x * blockDim.x + threadIdx.x;
  int nth = gridDim.x * blockDim.x;
  const float rs = 0.088388347648318447f;  // 1/sqrt(128)
  for (int idx = tid; idx < 6 * 8 * 4 * 64 * 8; idx += nth) {
    int j  = idx & 7;
    int ln = (idx >> 3) & 63;
    int kt = (idx >> 9) & 3;
    int vt = (idx >> 11) & 7;
    int d2 = idx >> 14;
    int v  = vt * 16 + (ln & 15);
    int k  = kt * 32 + (ln >> 4) * 8 + j;
    wF[idx] = f2bf(lin_w[(d2 * 128 + k) * 128 + v] * rs);
  }
  for (int idx = tid; idx < 128 * 16 * 20; idx += nth) {
    int v  = idx / 320;
    int r  = idx - v * 320;
    int ab = r / 20;
    int j  = r - ab * 20;
    int a = ab >> 2, b = ab & 3;
    float s = 0.f;
    if (j < 16) {
      int c = j >> 2, i = j & 3;
      const float* p = C3 + (((a * 4 + b) * 4 + c) * 4 + i) * 12;
      #pragma unroll
      for (int w = 0; w < 12; ++w) s += p[w] * w3[w * 128 + v];
    } else {
      int i = j - 16;
      const float* p = C2 + ((a * 4 + b) * 4 + i) * 5;
      #pragma unroll
      for (int w = 0; w < 5; ++w) s += p[w] * w2[w * 128 + v];
    }
    int byte_in_row = (ab * 48 + j * 2) ^ ((v & 7) << 4);   // swizzle baked in
    cc[v * 384 + (byte_in_row >> 1)] = (_Float16)s;
  }
  for (int idx = tid; idx < 128 * 16; idx += nth) {
    int v = idx >> 4;
    int ai = idx & 15;
    int a = ai >> 2, i = ai & 3;
    cu1[idx] = C1[(a * 4 + i) * 2 + 0] * w1[v] + C1[(a * 4 + i) * 2 + 1] * w1[128 + v];
  }
}

// ---------------- fused main: MFMA linear (y in regs) + LDS-fed fp32 contraction ------
// 512 threads = 8 waves; wave w owns vt = w (v = w*16 + vl). One 16-row tile per block.
// cc (98 KB) is staged to LDS once per block; contraction reads ~30cy LDS instead of
// ~260cy L2 (rounds 3-4 measured ~260cy exposed latency per cc load = bulk of the wall).
// LDS total 114,944 B -> 1 block/CU (8 waves). Static LDS >64KB is fine on gfx950.
__launch_bounds__(512, 2)
__global__ void main_kernel(const float* __restrict__ x,
                            const short* __restrict__ wF,
                            const _Float16* __restrict__ cc,
                            const float* __restrict__ cu1,
                            float* __restrict__ out) {
  __shared__ short xs[ROWS * XS_STRIDE];           // 16,640 B
  __shared__ __align__(16) char ccl[98304];        // 98,304 B, swizzled cc table

  const int t    = threadIdx.x;
  const int lane = t & 63;
  const int wave = t >> 6;      // 0..7 == vt
  const int vl   = lane & 15;
  const int quad = lane >> 4;   // 0..3
  const int n0   = blockIdx.x * ROWS;
  const int v    = wave * 16 + vl;

  // early issue: wF[d2=0] fragments + cu1 (hidden under staging + barrier)
  s16x8 bf_cur[4], bf_nxt[4];
  {
    const s16x8* w0 = (const s16x8*)wF + wave * 256 + lane;
    #pragma unroll
    for (int kt = 0; kt < 4; ++kt) bf_cur[kt] = w0[kt * 64];
  }
  f32x4 c1v[4];
  {
    const f32x4* cu1v = (const f32x4*)(cu1 + v * 16);
    #pragma unroll
    for (int q = 0; q < 4; ++q) c1v[q] = cu1v[q];
  }
  __builtin_amdgcn_sched_barrier(0);

  // stage x tile -> bf16 LDS (coalesced float4 loads)
  const float4* xsrc = (const float4*)(x + (size_t)n0 * 512);
  #pragma unroll
  for (int i2 = 0; i2 < 4; ++i2) {
    int f = i2 * 512 + t;          // float4 id, 0..2047
    float4 xv = xsrc[f];
    int row = f >> 7, c4 = f & 127;
    s16x4 pk;
    pk[0] = f2bf(xv.x); pk[1] = f2bf(xv.y); pk[2] = f2bf(xv.z); pk[3] = f2bf(xv.w);
    *(s16x4*)&xs[row * XS_STRIDE + c4 * 4] = pk;
  }

  // stage cc -> LDS: linear identity copy, 12 x 16B per thread, fully coalesced.
  {
    const f32x4* csrc = (const f32x4*)cc;
    f32x4*       cdst = (f32x4*)ccl;
    #pragma unroll
    for (int i = 0; i < 12; ++i) cdst[i * 512 + t] = csrc[i * 512 + t];
  }
  __syncthreads();

  // y[da][r]: da = d*4+a; this wave's v = wave*16+vl; row = quad*4+r
  float yreg[12][4];

  #pragma unroll
  for (int d2 = 0; d2 < 6; ++d2) {
    // prefetch next (d,blk) weight fragments; fence so they cannot sink into the MFMAs
    if (d2 < 5) {
      const s16x8* wsrc = (const s16x8*)wF + ((d2 + 1) * 8 + wave) * 256 + lane;
      #pragma unroll
      for (int kt = 0; kt < 4; ++kt) bf_nxt[kt] = wsrc[kt * 64];
    }
    __builtin_amdgcn_sched_barrier(0);
    const int d = d2 >> 1, blk = d2 & 1;
    const int a_begin = blk ? 1 : 0;
    const int a_end   = blk ? 4 : 1;
    #pragma unroll
    for (int a = a_begin; a < a_end; ++a) {
      f32x4 acc = {0.f, 0.f, 0.f, 0.f};
      #pragma unroll
      for (int kt = 0; kt < 4; ++kt) {
        s16x8 af = *(const s16x8*)&xs[vl * XS_STRIDE + a * 128 + kt * 32 + quad * 8];
        acc = __builtin_amdgcn_mfma_f32_16x16x32_bf16(af, bf_cur[kt], acc, 0, 0, 0);
      }
      const int da = d * 4 + a;
      #pragma unroll
      for (int r = 0; r < 4; ++r) yreg[da][r] = acc[r];
    }
    #pragma unroll
    for (int kt = 0; kt < 4; ++kt) bf_cur[kt] = bf_nxt[kt];
  }

  // ---------------- contraction (fp32 math, fp16 coeffs from swizzled LDS) ----------
  float acc[4][4];   // [i][r]

  // degree 1 (c1v loaded at kernel top)
  {
    float c1[16];
    #pragma unroll
    for (int q = 0; q < 4; ++q) {
      c1[4 * q + 0] = c1v[q][0]; c1[4 * q + 1] = c1v[q][1];
      c1[4 * q + 2] = c1v[q][2]; c1[4 * q + 3] = c1v[q][3];
    }
    #pragma unroll
    for (int i = 0; i < 4; ++i)
      #pragma unroll
      for (int r = 0; r < 4; ++r) {
        float s = c1[0 * 4 + i] * yreg[0][r];
        s = fmaf(c1[1 * 4 + i], yreg[1][r], s);
        s = fmaf(c1[2 * 4 + i], yreg[2][r], s);
        s = fmaf(c1[3 * 4 + i], yreg[3][r], s);
        acc[i][r] = s;
      }
  }

  // degrees 2+3: out[i] += G[ab] * (C2u[ab,i] + sum_c C3u[ab,c,i]*y3[c])
  const char* myc = ccl + v * 768;
  const int   vm  = (v & 7) << 4;
  #pragma unroll
  for (int ab = 0; ab < 16; ++ab) {
    h16x8 h0 = *(const h16x8*)(myc + ((ab * 48 +  0) ^ vm));
    h16x8 h1 = *(const h16x8*)(myc + ((ab * 48 + 16) ^ vm));
    h16x8 h2 = *(const h16x8*)(myc + ((ab * 48 + 32) ^ vm));
    const int a = ab >> 2, b = ab & 3;
    float cj[20];
    #pragma unroll
    for (int j = 0; j < 8; ++j) { cj[j] = (float)h0[j]; cj[8 + j] = (float)h1[j]; }
    #pragma unroll
    for (int j = 0; j < 4; ++j) cj[16 + j] = (float)h2[j];
    #pragma unroll
    for (int r = 0; r < 4; ++r) {
      const float G = yreg[a][r] * yreg[4 + b][r];
      #pragma unroll
      for (int i = 0; i < 4; ++i) {
        float s = cj[16 + i];
        s = fmaf(cj[0 + i],  yreg[8][r],  s);
        s = fmaf(cj[4 + i],  yreg[9][r],  s);
        s = fmaf(cj[8 + i],  yreg[10][r], s);
        s = fmaf(cj[12 + i], yreg[11][r], s);
        acc[i][r] = fmaf(G, s, acc[i][r]);
      }
    }
  }

  // store
  #pragma unroll
  for (int r = 0; r < 4; ++r) {
    const int n = n0 + quad * 4 + r;
    #pragma unroll
    for (int i = 0; i < 4; ++i) out[(size_t)n * 512 + i * 128 + v] = acc[i][r];
  }
}

extern "C" void kernel_launch(void* const* d_in, const int* in_sizes, int n_in,
                              void* d_out, int out_size, void* d_ws, size_t ws_size,
                              hipStream_t stream) {
  const float* x     = (const float*)d_in[0];
  const float* lin_w = (const float*)d_in[1];
  const float* w1    = (const float*)d_in[2];
  const float* w2    = (const float*)d_in[3];
  const float* w3    = (const float*)d_in[4];
  const float* C1    = (const float*)d_in[5];
  const float* C2    = (const float*)d_in[6];
  const float* C3    = (const float*)d_in[7];

  char* ws = (char*)d_ws;
  short*    wF  = (short*)ws;                     // 196608 B
  _Float16* cc  = (_Float16*)(ws + 196608);       //  98304 B (swizzled layout)
  float*    cu1 = (float*)(ws + 294912);          //   8192 B
  float*    out = (float*)d_out;

  hipLaunchKernelGGL(precompute_kernel, dim3(384), dim3(256), 0, stream,
                     lin_w, w1, w2, w3, C1, C2, C3, wF, cc, cu1);
  hipLaunchKernelGGL(main_kernel, dim3(2048), dim3(512), 0, stream,
                     x, wF, cc, cu1, out);
}

// Round 7
// 168.192 us; speedup vs baseline: 1.6017x; 1.1024x over previous
//
#include <hip/hip_runtime.h>

typedef __attribute__((ext_vector_type(4))) float    f32x4;
typedef __attribute__((ext_vector_type(4))) short    s16x4;
typedef __attribute__((ext_vector_type(8))) short    s16x8;
typedef __attribute__((ext_vector_type(8))) _Float16 h16x8;

#define ROWS 16
#define XS_STRIDE 520   // 512 + 8 bf16 pad
#define NTILE 8         // 2048 tiles / 256 blocks

__device__ __forceinline__ short f2bf(float f) {
  unsigned u = __float_as_uint(f);
  u = (u + 0x7fffu + ((u >> 16) & 1u)) >> 16;   // RNE
  return (short)u;
}

// ---------------- precompute (unchanged from round 6) ----------------
// wF[d2][vt][kt][lane][j] = lin_w[d2][k][v] / sqrt(128), bf16
// cc: per-v rows of 768 B (16 ab-groups x 48 B), fp16, XOR swizzle byte^=(v&7)<<4 baked in
// cu1[v][a*4+i] (f32)
__global__ void precompute_kernel(const float* __restrict__ lin_w,
                                  const float* __restrict__ w1,
                                  const float* __restrict__ w2,
                                  const float* __restrict__ w3,
                                  const float* __restrict__ C1,
                                  const float* __restrict__ C2,
                                  const float* __restrict__ C3,
                                  short*    __restrict__ wF,
                                  _Float16* __restrict__ cc,
                                  float*    __restrict__ cu1) {
  int tid = blockIdx.x * blockDim.x + threadIdx.x;
  int nth = gridDim.x * blockDim.x;
  const float rs = 0.088388347648318447f;  // 1/sqrt(128)
  for (int idx = tid; idx < 6 * 8 * 4 * 64 * 8; idx += nth) {
    int j  = idx & 7;
    int ln = (idx >> 3) & 63;
    int kt = (idx >> 9) & 3;
    int vt = (idx >> 11) & 7;
    int d2 = idx >> 14;
    int v  = vt * 16 + (ln & 15);
    int k  = kt * 32 + (ln >> 4) * 8 + j;
    wF[idx] = f2bf(lin_w[(d2 * 128 + k) * 128 + v] * rs);
  }
  for (int idx = tid; idx < 128 * 16 * 20; idx += nth) {
    int v  = idx / 320;
    int r  = idx - v * 320;
    int ab = r / 20;
    int j  = r - ab * 20;
    int a = ab >> 2, b = ab & 3;
    float s = 0.f;
    if (j < 16) {
      int c = j >> 2, i = j & 3;
      const float* p = C3 + (((a * 4 + b) * 4 + c) * 4 + i) * 12;
      #pragma unroll
      for (int w = 0; w < 12; ++w) s += p[w] * w3[w * 128 + v];
    } else {
      int i = j - 16;
      const float* p = C2 + ((a * 4 + b) * 4 + i) * 5;
      #pragma unroll
      for (int w = 0; w < 5; ++w) s += p[w] * w2[w * 128 + v];
    }
    int byte_in_row = (ab * 48 + j * 2) ^ ((v & 7) << 4);   // swizzle baked in
    cc[v * 384 + (byte_in_row >> 1)] = (_Float16)s;
  }
  for (int idx = tid; idx < 128 * 16; idx += nth) {
    int v = idx >> 4;
    int ai = idx & 15;
    int a = ai >> 2, i = ai & 3;
    cu1[idx] = C1[(a * 4 + i) * 2 + 0] * w1[v] + C1[(a * 4 + i) * 2 + 1] * w1[128 + v];
  }
}

// ---------------- persistent fused main ----------------
// 256 blocks (1/CU at this LDS) x 512 threads x NTILE tiles each.
// Prologue ONCE per block: cc->LDS (98KB), cu1->regs, ALL 24 wF fragments->regs
// (96 VGPR — free, occupancy is LDS-limited at 2 waves/SIMD). Per-tile loop has
// ZERO weight/coeff global loads; x tile k+1 prefetched to regs at top of iter k
// (T14 split), written to the other LDS buffer after the contraction.
__launch_bounds__(512, 2)
__global__ void main_kernel(const float* __restrict__ x,
                            const short* __restrict__ wF,
                            const _Float16* __restrict__ cc,
                            const float* __restrict__ cu1,
                            float* __restrict__ out) {
  __shared__ short xs[2][ROWS * XS_STRIDE];        // 2 x 16,640 B
  __shared__ __align__(16) char ccl[98304];        // swizzled cc table

  const int t    = threadIdx.x;
  const int lane = t & 63;
  const int wave = t >> 6;      // 0..7 == vt
  const int vl   = lane & 15;
  const int quad = lane >> 4;   // 0..3
  const int b    = blockIdx.x;  // 0..255
  const int v    = wave * 16 + vl;

  // ---- prologue: issue all resident-state loads, then stage, one barrier ----
  // 1) all wF fragments for this wave's vt: 24 x s16x8 (96 VGPR, held all kernel)
  s16x8 wreg[6][4];
  #pragma unroll
  for (int d2 = 0; d2 < 6; ++d2) {
    const s16x8* wsrc = (const s16x8*)wF + (d2 * 8 + wave) * 256 + lane;
    #pragma unroll
    for (int kt = 0; kt < 4; ++kt) wreg[d2][kt] = wsrc[kt * 64];
  }
  // 2) cu1
  f32x4 c1v[4];
  {
    const f32x4* cu1v = (const f32x4*)(cu1 + v * 16);
    #pragma unroll
    for (int q = 0; q < 4; ++q) c1v[q] = cu1v[q];
  }
  // 3) cc -> LDS (linear identity copy, swizzle baked into global layout)
  {
    const f32x4* csrc = (const f32x4*)cc;
    f32x4*       cdst = (f32x4*)ccl;
    #pragma unroll
    for (int i = 0; i < 12; ++i) cdst[i * 512 + t] = csrc[i * 512 + t];
  }
  // 4) x tile 0 -> xs[0]
  {
    const float4* xsrc = (const float4*)(x + (size_t)b * ROWS * 512);
    #pragma unroll
    for (int i2 = 0; i2 < 4; ++i2) {
      int f = i2 * 512 + t;
      float4 xv = xsrc[f];
      int row = f >> 7, c4 = f & 127;
      s16x4 pk;
      pk[0] = f2bf(xv.x); pk[1] = f2bf(xv.y); pk[2] = f2bf(xv.z); pk[3] = f2bf(xv.w);
      *(s16x4*)&xs[0][row * XS_STRIDE + c4 * 4] = pk;
    }
  }
  __syncthreads();

  float4 xp[4];
  #pragma unroll 1
  for (int k = 0; k < NTILE; ++k) {
    const int cur = k & 1;
    const int n0  = (k * 256 + b) * ROWS;

    // prefetch next x tile into regs (latency hides under MFMA + contraction)
    if (k + 1 < NTILE) {
      const float4* xsrc = (const float4*)(x + (size_t)((k + 1) * 256 + b) * ROWS * 512);
      #pragma unroll
      for (int i2 = 0; i2 < 4; ++i2) xp[i2] = xsrc[i2 * 512 + t];
    }
    __builtin_amdgcn_sched_barrier(0);

    // ---- MFMA phase: all operands reg/LDS-resident, zero loads ----
    float yreg[12][4];
    #pragma unroll
    for (int d2 = 0; d2 < 6; ++d2) {
      const int d = d2 >> 1, blk = d2 & 1;
      const int a_begin = blk ? 1 : 0;
      const int a_end   = blk ? 4 : 1;
      #pragma unroll
      for (int a = a_begin; a < a_end; ++a) {
        f32x4 acc4 = {0.f, 0.f, 0.f, 0.f};
        #pragma unroll
        for (int kt = 0; kt < 4; ++kt) {
          s16x8 af = *(const s16x8*)&xs[cur][vl * XS_STRIDE + a * 128 + kt * 32 + quad * 8];
          acc4 = __builtin_amdgcn_mfma_f32_16x16x32_bf16(af, wreg[d2][kt], acc4, 0, 0, 0);
        }
        const int da = d * 4 + a;
        #pragma unroll
        for (int r = 0; r < 4; ++r) yreg[da][r] = acc4[r];
      }
    }

    // ---- contraction (fp32 math, fp16 coeffs from swizzled LDS) ----
    float acc[4][4];   // [i][r]
    {
      float c1[16];
      #pragma unroll
      for (int q = 0; q < 4; ++q) {
        c1[4 * q + 0] = c1v[q][0]; c1[4 * q + 1] = c1v[q][1];
        c1[4 * q + 2] = c1v[q][2]; c1[4 * q + 3] = c1v[q][3];
      }
      #pragma unroll
      for (int i = 0; i < 4; ++i)
        #pragma unroll
        for (int r = 0; r < 4; ++r) {
          float s = c1[0 * 4 + i] * yreg[0][r];
          s = fmaf(c1[1 * 4 + i], yreg[1][r], s);
          s = fmaf(c1[2 * 4 + i], yreg[2][r], s);
          s = fmaf(c1[3 * 4 + i], yreg[3][r], s);
          acc[i][r] = s;
        }
    }

    const char* myc = ccl + v * 768;
    const int   vm  = (v & 7) << 4;
    #pragma unroll
    for (int ab = 0; ab < 16; ++ab) {
      h16x8 h0 = *(const h16x8*)(myc + ((ab * 48 +  0) ^ vm));
      h16x8 h1 = *(const h16x8*)(myc + ((ab * 48 + 16) ^ vm));
      h16x8 h2 = *(const h16x8*)(myc + ((ab * 48 + 32) ^ vm));
      const int a = ab >> 2, b2 = ab & 3;
      float cj[20];
      #pragma unroll
      for (int j = 0; j < 8; ++j) { cj[j] = (float)h0[j]; cj[8 + j] = (float)h1[j]; }
      #pragma unroll
      for (int j = 0; j < 4; ++j) cj[16 + j] = (float)h2[j];
      #pragma unroll
      for (int r = 0; r < 4; ++r) {
        const float G = yreg[a][r] * yreg[4 + b2][r];
        #pragma unroll
        for (int i = 0; i < 4; ++i) {
          float s = cj[16 + i];
          s = fmaf(cj[0 + i],  yreg[8][r],  s);
          s = fmaf(cj[4 + i],  yreg[9][r],  s);
          s = fmaf(cj[8 + i],  yreg[10][r], s);
          s = fmaf(cj[12 + i], yreg[11][r], s);
          acc[i][r] = fmaf(G, s, acc[i][r]);
        }
      }
    }

    // store this tile
    #pragma unroll
    for (int r = 0; r < 4; ++r) {
      const int n = n0 + quad * 4 + r;
      #pragma unroll
      for (int i = 0; i < 4; ++i) out[(size_t)n * 512 + i * 128 + v] = acc[i][r];
    }

    // write prefetched tile into the other buffer (safe: all reads of that buffer
    // finished before the previous iteration's barrier)
    if (k + 1 < NTILE) {
      #pragma unroll
      for (int i2 = 0; i2 < 4; ++i2) {
        int f = i2 * 512 + t;
        int row = f >> 7, c4 = f & 127;
        s16x4 pk;
        pk[0] = f2bf(xp[i2].x); pk[1] = f2bf(xp[i2].y);
        pk[2] = f2bf(xp[i2].z); pk[3] = f2bf(xp[i2].w);
        *(s16x4*)&xs[1 - cur][row * XS_STRIDE + c4 * 4] = pk;
      }
    }
    __syncthreads();
  }
}

extern "C" void kernel_launch(void* const* d_in, const int* in_sizes, int n_in,
                              void* d_out, int out_size, void* d_ws, size_t ws_size,
                              hipStream_t stream) {
  const float* x     = (const float*)d_in[0];
  const float* lin_w = (const float*)d_in[1];
  const float* w1    = (const float*)d_in[2];
  const float* w2    = (const float*)d_in[3];
  const float* w3    = (const float*)d_in[4];
  const float* C1    = (const float*)d_in[5];
  const float* C2    = (const float*)d_in[6];
  const float* C3    = (const float*)d_in[7];

  char* ws = (char*)d_ws;
  short*    wF  = (short*)ws;                     // 196608 B
  _Float16* cc  = (_Float16*)(ws + 196608);       //  98304 B (swizzled layout)
  float*    cu1 = (float*)(ws + 294912);          //   8192 B
  float*    out = (float*)d_out;

  hipLaunchKernelGGL(precompute_kernel, dim3(384), dim3(256), 0, stream,
                     lin_w, w1, w2, w3, C1, C2, C3, wF, cc, cu1);
  hipLaunchKernelGGL(main_kernel, dim3(256), dim3(512), 0, stream,
                     x, wF, cc, cu1, out);
}

// Round 8
// 166.709 us; speedup vs baseline: 1.6160x; 1.0089x over previous
//
#include <hip/hip_runtime.h>

typedef __attribute__((ext_vector_type(4))) float    f32x4;
typedef __attribute__((ext_vector_type(4))) short    s16x4;
typedef __attribute__((ext_vector_type(8))) short    s16x8;
typedef __attribute__((ext_vector_type(8))) _Float16 h16x8;

#define ROWS 16
#define XS_STRIDE 520   // 512 + 8 bf16 pad
#define NTILE 8         // 2048 tiles / 256 blocks

__device__ __forceinline__ short f2bf(float f) {
  unsigned u = __float_as_uint(f);
  u = (u + 0x7fffu + ((u >> 16) & 1u)) >> 16;   // RNE
  return (short)u;
}

// ---------------- precompute (unchanged from round 6) ----------------
// wF[d2][vt][kt][lane][j] = lin_w[d2][k][v] / sqrt(128), bf16
// cc: per-v rows of 768 B (16 ab-groups x 48 B), fp16, XOR swizzle byte^=(v&7)<<4 baked in
// cu1[v][a*4+i] (f32)
__global__ void precompute_kernel(const float* __restrict__ lin_w,
                                  const float* __restrict__ w1,
                                  const float* __restrict__ w2,
                                  const float* __restrict__ w3,
                                  const float* __restrict__ C1,
                                  const float* __restrict__ C2,
                                  const float* __restrict__ C3,
                                  short*    __restrict__ wF,
                                  _Float16* __restrict__ cc,
                                  float*    __restrict__ cu1) {
  int tid = blockIdx.x * blockDim.x + threadIdx.x;
  int nth = gridDim.x * blockDim.x;
  const float rs = 0.088388347648318447f;  // 1/sqrt(128)
  for (int idx = tid; idx < 6 * 8 * 4 * 64 * 8; idx += nth) {
    int j  = idx & 7;
    int ln = (idx >> 3) & 63;
    int kt = (idx >> 9) & 3;
    int vt = (idx >> 11) & 7;
    int d2 = idx >> 14;
    int v  = vt * 16 + (ln & 15);
    int k  = kt * 32 + (ln >> 4) * 8 + j;
    wF[idx] = f2bf(lin_w[(d2 * 128 + k) * 128 + v] * rs);
  }
  for (int idx = tid; idx < 128 * 16 * 20; idx += nth) {
    int v  = idx / 320;
    int r  = idx - v * 320;
    int ab = r / 20;
    int j  = r - ab * 20;
    int a = ab >> 2, b = ab & 3;
    float s = 0.f;
    if (j < 16) {
      int c = j >> 2, i = j & 3;
      const float* p = C3 + (((a * 4 + b) * 4 + c) * 4 + i) * 12;
      #pragma unroll
      for (int w = 0; w < 12; ++w) s += p[w] * w3[w * 128 + v];
    } else {
      int i = j - 16;
      const float* p = C2 + ((a * 4 + b) * 4 + i) * 5;
      #pragma unroll
      for (int w = 0; w < 5; ++w) s += p[w] * w2[w * 128 + v];
    }
    int byte_in_row = (ab * 48 + j * 2) ^ ((v & 7) << 4);   // swizzle baked in
    cc[v * 384 + (byte_in_row >> 1)] = (_Float16)s;
  }
  for (int idx = tid; idx < 128 * 16; idx += nth) {
    int v = idx >> 4;
    int ai = idx & 15;
    int a = ai >> 2, i = ai & 3;
    cu1[idx] = C1[(a * 4 + i) * 2 + 0] * w1[v] + C1[(a * 4 + i) * 2 + 1] * w1[128 + v];
  }
}

// ---------------- persistent fused main, barrier off the store path ----------------
// 256 blocks (1/CU) x 512 threads x NTILE tiles. Resident state loaded once:
// cc->LDS (98KB), cu1->regs, all 24 wF fragments->regs. Per tile:
//   ds_write next-x -> other buffer; MFMA on current; BARRIER; issue x prefetch k+2;
//   contraction; stores.  The single barrier drains prior-iter stores only after
// they had a ds_write+MFMA phase to land (round-7 regression was the barrier
// draining stores immediately after issue).
__launch_bounds__(512, 2)
__global__ void main_kernel(const float* __restrict__ x,
                            const short* __restrict__ wF,
                            const _Float16* __restrict__ cc,
                            const float* __restrict__ cu1,
                            float* __restrict__ out) {
  __shared__ short xs[2][ROWS * XS_STRIDE];        // 2 x 16,640 B
  __shared__ __align__(16) char ccl[98304];        // swizzled cc table

  const int t    = threadIdx.x;
  const int lane = t & 63;
  const int wave = t >> 6;      // 0..7 == vt
  const int vl   = lane & 15;
  const int quad = lane >> 4;   // 0..3
  const int b    = blockIdx.x;  // 0..255
  const int v    = wave * 16 + vl;

  // ---- prologue ----
  s16x8 wreg[6][4];
  #pragma unroll
  for (int d2 = 0; d2 < 6; ++d2) {
    const s16x8* wsrc = (const s16x8*)wF + (d2 * 8 + wave) * 256 + lane;
    #pragma unroll
    for (int kt = 0; kt < 4; ++kt) wreg[d2][kt] = wsrc[kt * 64];
  }
  f32x4 c1v[4];
  {
    const f32x4* cu1v = (const f32x4*)(cu1 + v * 16);
    #pragma unroll
    for (int q = 0; q < 4; ++q) c1v[q] = cu1v[q];
  }
  {
    const f32x4* csrc = (const f32x4*)cc;
    f32x4*       cdst = (f32x4*)ccl;
    #pragma unroll
    for (int i = 0; i < 12; ++i) cdst[i * 512 + t] = csrc[i * 512 + t];
  }
  // x tile 0 -> xs[0]
  {
    const float4* xsrc = (const float4*)(x + (size_t)b * ROWS * 512);
    #pragma unroll
    for (int i2 = 0; i2 < 4; ++i2) {
      int f = i2 * 512 + t;
      float4 xv = xsrc[f];
      int row = f >> 7, c4 = f & 127;
      s16x4 pk;
      pk[0] = f2bf(xv.x); pk[1] = f2bf(xv.y); pk[2] = f2bf(xv.z); pk[3] = f2bf(xv.w);
      *(s16x4*)&xs[0][row * XS_STRIDE + c4 * 4] = pk;
    }
  }
  // prefetch x tile 1 into regs
  float4 xp[4];
  {
    const float4* xsrc = (const float4*)(x + (size_t)(256 + b) * ROWS * 512);
    #pragma unroll
    for (int i2 = 0; i2 < 4; ++i2) xp[i2] = xsrc[i2 * 512 + t];
  }
  __syncthreads();

  #pragma unroll 2
  for (int k = 0; k < NTILE; ++k) {
    const int cur = k & 1;
    const int n0  = (k * 256 + b) * ROWS;

    // 1) write prefetched tile k+1 into the other buffer (reads of it start next iter)
    if (k + 1 < NTILE) {
      #pragma unroll
      for (int i2 = 0; i2 < 4; ++i2) {
        int f = i2 * 512 + t;
        int row = f >> 7, c4 = f & 127;
        s16x4 pk;
        pk[0] = f2bf(xp[i2].x); pk[1] = f2bf(xp[i2].y);
        pk[2] = f2bf(xp[i2].z); pk[3] = f2bf(xp[i2].w);
        *(s16x4*)&xs[1 - cur][row * XS_STRIDE + c4 * 4] = pk;
      }
    }

    // 2) MFMA phase: all operands reg/LDS-resident
    float yreg[12][4];
    #pragma unroll
    for (int d2 = 0; d2 < 6; ++d2) {
      const int d = d2 >> 1, blk = d2 & 1;
      const int a_begin = blk ? 1 : 0;
      const int a_end   = blk ? 4 : 1;
      #pragma unroll
      for (int a = a_begin; a < a_end; ++a) {
        f32x4 acc4 = {0.f, 0.f, 0.f, 0.f};
        #pragma unroll
        for (int kt = 0; kt < 4; ++kt) {
          s16x8 af = *(const s16x8*)&xs[cur][vl * XS_STRIDE + a * 128 + kt * 32 + quad * 8];
          acc4 = __builtin_amdgcn_mfma_f32_16x16x32_bf16(af, wreg[d2][kt], acc4, 0, 0, 0);
        }
        const int da = d * 4 + a;
        #pragma unroll
        for (int r = 0; r < 4; ++r) yreg[da][r] = acc4[r];
      }
    }

    // 3) barrier: ds_writes visible; xs[cur] reads done; k-1 stores drained (hidden)
    __syncthreads();

    // 4) issue x prefetch for tile k+2 (lands during the contraction)
    if (k + 2 < NTILE) {
      const float4* xsrc = (const float4*)(x + (size_t)((k + 2) * 256 + b) * ROWS * 512);
      #pragma unroll
      for (int i2 = 0; i2 < 4; ++i2) xp[i2] = xsrc[i2 * 512 + t];
    }
    __builtin_amdgcn_sched_barrier(0);

    // 5) contraction (fp32 math, fp16 coeffs from swizzled LDS)
    float acc[4][4];   // [i][r]
    {
      float c1[16];
      #pragma unroll
      for (int q = 0; q < 4; ++q) {
        c1[4 * q + 0] = c1v[q][0]; c1[4 * q + 1] = c1v[q][1];
        c1[4 * q + 2] = c1v[q][2]; c1[4 * q + 3] = c1v[q][3];
      }
      #pragma unroll
      for (int i = 0; i < 4; ++i)
        #pragma unroll
        for (int r = 0; r < 4; ++r) {
          float s = c1[0 * 4 + i] * yreg[0][r];
          s = fmaf(c1[1 * 4 + i], yreg[1][r], s);
          s = fmaf(c1[2 * 4 + i], yreg[2][r], s);
          s = fmaf(c1[3 * 4 + i], yreg[3][r], s);
          acc[i][r] = s;
        }
    }

    const char* myc = ccl + v * 768;
    const int   vm  = (v & 7) << 4;
    #pragma unroll
    for (int ab = 0; ab < 16; ++ab) {
      h16x8 h0 = *(const h16x8*)(myc + ((ab * 48 +  0) ^ vm));
      h16x8 h1 = *(const h16x8*)(myc + ((ab * 48 + 16) ^ vm));
      h16x8 h2 = *(const h16x8*)(myc + ((ab * 48 + 32) ^ vm));
      const int a = ab >> 2, b2 = ab & 3;
      float cj[20];
      #pragma unroll
      for (int j = 0; j < 8; ++j) { cj[j] = (float)h0[j]; cj[8 + j] = (float)h1[j]; }
      #pragma unroll
      for (int j = 0; j < 4; ++j) cj[16 + j] = (float)h2[j];
      #pragma unroll
      for (int r = 0; r < 4; ++r) {
        const float G = yreg[a][r] * yreg[4 + b2][r];
        #pragma unroll
        for (int i = 0; i < 4; ++i) {
          float s = cj[16 + i];
          s = fmaf(cj[0 + i],  yreg[8][r],  s);
          s = fmaf(cj[4 + i],  yreg[9][r],  s);
          s = fmaf(cj[8 + i],  yreg[10][r], s);
          s = fmaf(cj[12 + i], yreg[11][r], s);
          acc[i][r] = fmaf(G, s, acc[i][r]);
        }
      }
    }

    // 6) store tile k (drains at NEXT iteration's barrier, hidden under ds_write+MFMA)
    #pragma unroll
    for (int r = 0; r < 4; ++r) {
      const int n = n0 + quad * 4 + r;
      #pragma unroll
      for (int i = 0; i < 4; ++i) out[(size_t)n * 512 + i * 128 + v] = acc[i][r];
    }
  }
}

extern "C" void kernel_launch(void* const* d_in, const int* in_sizes, int n_in,
                              void* d_out, int out_size, void* d_ws, size_t ws_size,
                              hipStream_t stream) {
  const float* x     = (const float*)d_in[0];
  const float* lin_w = (const float*)d_in[1];
  const float* w1    = (const float*)d_in[2];
  const float* w2    = (const float*)d_in[3];
  const float* w3    = (const float*)d_in[4];
  const float* C1    = (const float*)d_in[5];
  const float* C2    = (const float*)d_in[6];
  const float* C3    = (const float*)d_in[7];

  char* ws = (char*)d_ws;
  short*    wF  = (short*)ws;                     // 196608 B
  _Float16* cc  = (_Float16*)(ws + 196608);       //  98304 B (swizzled layout)
  float*    cu1 = (float*)(ws + 294912);          //   8192 B
  float*    out = (float*)d_out;

  hipLaunchKernelGGL(precompute_kernel, dim3(384), dim3(256), 0, stream,
                     lin_w, w1, w2, w3, C1, C2, C3, wF, cc, cu1);
  hipLaunchKernelGGL(main_kernel, dim3(256), dim3(512), 0, stream,
                     x, wF, cc, cu1, out);
}